// Round 4
// baseline (1929.720 us; speedup 1.0000x reference)
//
#include <hip/hip_runtime.h>
#include <hip/hip_bf16.h>

typedef __hip_bfloat16 bf16;
typedef __bf16 bf16x8 __attribute__((ext_vector_type(8)));
typedef float f32x4 __attribute__((ext_vector_type(4)));

#define B_  2
#define L_  2048
#define D_  1024
#define DIN 2048
#define NST 16
#define T_  (B_ * L_)   // 4096 tokens

// Static fallback scratch if harness d_ws is too small (~124.5 MiB needed).
#define WS_NEEDED 130548000ull
__device__ __align__(256) char g_scratch[138412032];   // 132 MiB

__device__ __forceinline__ float b2f(bf16 v) { return __bfloat162float(v); }
__device__ __forceinline__ bf16 f2b(float v) { return __float2bfloat16(v); }

// ---------------------------------------------------------------- transpose + fp32->bf16
// in: R x C (row-major fp32) -> out: C x R (row-major bf16)
__global__ __launch_bounds__(256) void transpose_f2b(const float* __restrict__ in,
                                                     bf16* __restrict__ out, int R, int C) {
    __shared__ float t[32][33];
    int c0 = blockIdx.x * 32, r0 = blockIdx.y * 32;
    int tx = threadIdx.x & 31, ty = threadIdx.x >> 5;   // 32 x 8
    #pragma unroll
    for (int i = 0; i < 32; i += 8)
        t[ty + i][tx] = in[(size_t)(r0 + ty + i) * C + c0 + tx];
    __syncthreads();
    #pragma unroll
    for (int i = 0; i < 32; i += 8)
        out[(size_t)(c0 + ty + i) * R + r0 + tx] = f2b(t[tx][ty + i]);
}

// ---------------------------------------------------------------- layernorm (fp32 in, bf16 out)
__global__ __launch_bounds__(256) void ln_kernel(const float* __restrict__ x,
                                                 const float* __restrict__ w,
                                                 const float* __restrict__ bb,
                                                 bf16* __restrict__ xn) {
    int tok = blockIdx.x, tid = threadIdx.x;
    const float* xr = x + (size_t)tok * D_;
    float4 v4 = ((const float4*)xr)[tid];
    float v[4] = {v4.x, v4.y, v4.z, v4.w};
    float s = 0.f, ss = 0.f;
    #pragma unroll
    for (int i = 0; i < 4; i++) { s += v[i]; ss += v[i] * v[i]; }
    #pragma unroll
    for (int o = 32; o > 0; o >>= 1) { s += __shfl_down(s, o); ss += __shfl_down(ss, o); }
    __shared__ float rs[4], rss[4], mv[2];
    if ((tid & 63) == 0) { rs[tid >> 6] = s; rss[tid >> 6] = ss; }
    __syncthreads();
    if (tid == 0) {
        float S = rs[0] + rs[1] + rs[2] + rs[3];
        float SS = rss[0] + rss[1] + rss[2] + rss[3];
        float mu = S * (1.f / D_);
        float var = SS * (1.f / D_) - mu * mu;
        mv[0] = mu; mv[1] = rsqrtf(fmaxf(var, 0.f) + 1e-5f);
    }
    __syncthreads();
    float mu = mv[0], rstd = mv[1];
    float4 wv = ((const float4*)w)[tid];
    float4 bv = ((const float4*)bb)[tid];
    float wa[4] = {wv.x, wv.y, wv.z, wv.w};
    float ba[4] = {bv.x, bv.y, bv.z, bv.w};
    union { uint2 u; bf16 h[4]; } q;
    #pragma unroll
    for (int i = 0; i < 4; i++)
        q.h[i] = f2b((v[i] - mu) * rstd * wa[i] + ba[i]);
    ((uint2*)(xn + (size_t)tok * D_))[tid] = q.u;
}

// ---------------------------------------------------------------- GEMM 128x128, register-staged LDS
// C[M,N] = A[M,K] @ Bt[N,K]^T
// EPI 0: store bf16 | 1: +bias(fp32), softplus, store fp32 | 2: +resid(fp32), store fp32
template <int EPI>
__global__ __launch_bounds__(256) void gemm128(const bf16* __restrict__ A,
                                               const bf16* __restrict__ Bt,
                                               int K, void* __restrict__ Cout,
                                               const float* __restrict__ extra, int ldc) {
    __shared__ __align__(16) bf16 As[128 * 32];
    __shared__ __align__(16) bf16 Bs[128 * 32];
    const int tid = threadIdx.x;
    const int lane = tid & 63;
    const int wave = tid >> 6;
    const int bm = blockIdx.y * 128, bn = blockIdx.x * 128;
    const int wm = (wave & 1) * 64, wn = (wave >> 1) * 64;
    f32x4 acc[4][4];
    #pragma unroll
    for (int i = 0; i < 4; i++)
        #pragma unroll
        for (int j = 0; j < 4; j++) acc[i][j] = (f32x4){0.f, 0.f, 0.f, 0.f};

    const int r = tid >> 2;   // 0..63: row within 64-row half
    const int c = tid & 3;    // 16B chunk within 64B (32-element) k-slab
    const bf16* ga  = A  + (size_t)(bm + r) * K + c * 8;
    const bf16* gb  = Bt + (size_t)(bn + r) * K + c * 8;
    const bf16* ga2 = ga + (size_t)64 * K;
    const bf16* gb2 = gb + (size_t)64 * K;
    bf16* la  = As + tid * 8;           // element (r*32 + c*8) = row-major [64][32]
    bf16* lb  = Bs + tid * 8;
    bf16* la2 = la + 64 * 32;
    bf16* lb2 = lb + 64 * 32;

    const int fm = lane & 15;
    const int fk = (lane >> 4) * 8;

    for (int k0 = 0; k0 < K; k0 += 32) {
        uint4 va  = *(const uint4*)(ga  + k0);
        uint4 va2 = *(const uint4*)(ga2 + k0);
        uint4 vb  = *(const uint4*)(gb  + k0);
        uint4 vb2 = *(const uint4*)(gb2 + k0);
        __syncthreads();                 // prior iteration's LDS reads complete
        *(uint4*)la  = va;
        *(uint4*)la2 = va2;
        *(uint4*)lb  = vb;
        *(uint4*)lb2 = vb2;
        __syncthreads();                 // stores visible to all waves
        bf16x8 af[4], bfr[4];
        #pragma unroll
        for (int i = 0; i < 4; i++)
            af[i] = *(const bf16x8*)(As + (wm + i * 16 + fm) * 32 + fk);
        #pragma unroll
        for (int j = 0; j < 4; j++)
            bfr[j] = *(const bf16x8*)(Bs + (wn + j * 16 + fm) * 32 + fk);
        #pragma unroll
        for (int i = 0; i < 4; i++)
            #pragma unroll
            for (int j = 0; j < 4; j++)
                acc[i][j] = __builtin_amdgcn_mfma_f32_16x16x32_bf16(af[i], bfr[j], acc[i][j], 0, 0, 0);
    }

    const int cn = lane & 15;
    const int r4 = (lane >> 4) * 4;
    #pragma unroll
    for (int i = 0; i < 4; i++) {
        #pragma unroll
        for (int j = 0; j < 4; j++) {
            int row = bm + wm + i * 16 + r4;
            int col = bn + wn + j * 16 + cn;
            #pragma unroll
            for (int rr = 0; rr < 4; rr++) {
                float v = acc[i][j][rr];
                size_t idx = (size_t)(row + rr) * ldc + col;
                if (EPI == 0) {
                    ((bf16*)Cout)[idx] = f2b(v);
                } else if (EPI == 1) {
                    v += extra[col];
                    float sp = (v > 15.f) ? v : log1pf(__expf(v));
                    sp = fminf(fmaxf(sp, 0.f), 60.f);      // inert clamp
                    ((float*)Cout)[idx] = sp;
                } else {
                    v += extra[idx];
                    ((float*)Cout)[idx] = v;
                }
            }
        }
    }
}

// ---------------------------------------------------------------- depthwise causal conv + SiLU
// xz: (T, 2*DIN) bf16, x_path = cols [0,DIN). out xs: (T, DIN) bf16
__global__ __launch_bounds__(256) void conv_kernel(const bf16* __restrict__ xz,
                                                   const float* __restrict__ wconv,
                                                   const float* __restrict__ bconv,
                                                   bf16* __restrict__ xs) {
    int d = blockIdx.x * 256 + threadIdx.x;   // 0..DIN-1
    int b = blockIdx.z;
    int l0 = blockIdx.y * 128;
    float w0 = wconv[d * 4 + 0];
    float w1 = wconv[d * 4 + 1];
    float w2 = wconv[d * 4 + 2];
    float w3 = wconv[d * 4 + 3];
    float bc = bconv[d];
    const bf16* base = xz + (size_t)(b * L_) * (2 * DIN) + d;
    float xm3 = (l0 >= 3) ? b2f(base[(size_t)(l0 - 3) * (2 * DIN)]) : 0.f;
    float xm2 = (l0 >= 2) ? b2f(base[(size_t)(l0 - 2) * (2 * DIN)]) : 0.f;
    float xm1 = (l0 >= 1) ? b2f(base[(size_t)(l0 - 1) * (2 * DIN)]) : 0.f;
    for (int l = l0; l < l0 + 128; ++l) {
        float cur = b2f(base[(size_t)l * (2 * DIN)]);
        float v = fmaf(w0, xm3, fmaf(w1, xm2, fmaf(w2, xm1, fmaf(w3, cur, bc))));
        float s = v / (1.f + __expf(-v));
        s = fminf(fmaxf(s, -1e4f), 1e4f);                  // inert clamp
        xs[(size_t)(b * L_ + l) * DIN + d] = f2b(s);
        xm3 = xm2; xm2 = xm1; xm1 = cur;
    }
}

// ---------------------------------------------------------------- B/C projections (N=16 each)
__global__ __launch_bounds__(256) void bc_kernel(const bf16* __restrict__ xs,
                                                 const float* __restrict__ wb,
                                                 const float* __restrict__ wc,
                                                 float* __restrict__ Bq, float* __restrict__ Cq) {
    int tok = blockIdx.x;
    __shared__ float xr[DIN];
    __shared__ float red[8][32];
    const bf16* row = xs + (size_t)tok * DIN;
    {
        union { uint4 u; bf16 h[8]; } p;
        p.u = ((const uint4*)row)[threadIdx.x];
        #pragma unroll
        for (int i = 0; i < 8; i++) xr[threadIdx.x * 8 + i] = b2f(p.h[i]);
    }
    __syncthreads();
    int n = threadIdx.x & 31, g = threadIdx.x >> 5;
    const float* w = (n < 16) ? (wb + n) : (wc + (n - 16));
    float p = 0.f;
    int k0 = g * 256;
    for (int k = k0; k < k0 + 256; ++k) p += xr[k] * w[(size_t)k * 16];
    red[g][n] = p;
    __syncthreads();
    if (g == 0) {
        float s = 0.f;
        #pragma unroll
        for (int i = 0; i < 8; i++) s += red[i][n];
        if (n < 16) Bq[(size_t)tok * 16 + n] = s;
        else        Cq[(size_t)tok * 16 + (n - 16)] = s;
    }
}

// ---------------------------------------------------------------- selective scan (+gating)
// one 16-lane group per (b,d) channel; lane = state index n
__global__ __launch_bounds__(256) void scan_kernel(const float* __restrict__ delta,
                                                   const bf16* __restrict__ xs,
                                                   const float* __restrict__ Bq,
                                                   const float* __restrict__ Cq,
                                                   const float* __restrict__ A_log,
                                                   const float* __restrict__ Dp,
                                                   const bf16* __restrict__ xz,
                                                   bf16* __restrict__ gbuf) {
    int grp = (blockIdx.x * 256 + threadIdx.x) >> 4;   // 0..4095
    int n = threadIdx.x & 15;
    int b = grp >> 11;
    int d = grp & (DIN - 1);
    float A = -__expf(A_log[d * 16 + n]);
    float Dd = Dp[d];
    float h = 0.f;
    int tokbase = b * L_;
    for (int t = 0; t < L_; ++t) {
        int tok = tokbase + t;
        float dlt = fminf(fmaxf(delta[(size_t)tok * DIN + d], 0.f), 60.f);
        float xv  = b2f(xs[(size_t)tok * DIN + d]);
        float Bv  = Bq[(size_t)tok * 16 + n];
        float Cv  = Cq[(size_t)tok * 16 + n];
        float a = __expf(fmaxf(dlt * A, -80.f));
        h = fmaf(a, h, dlt * xv * Bv);
        float s = h * Cv;
        s += __shfl_xor(s, 1);
        s += __shfl_xor(s, 2);
        s += __shfl_xor(s, 4);
        s += __shfl_xor(s, 8);
        if (n == 0) {
            float zv = b2f(xz[(size_t)tok * (2 * DIN) + DIN + d]);
            float y = s + Dd * xv;
            float gg = y * (zv / (1.f + __expf(-zv)));
            gg = fminf(fmaxf(gg, -1e5f), 1e5f);            // inert clamp
            gbuf[(size_t)tok * DIN + d] = f2b(gg);
        }
    }
}

// ---------------------------------------------------------------- launch
extern "C" void kernel_launch(void* const* d_in, const int* in_sizes, int n_in,
                              void* d_out, int out_size, void* d_ws, size_t ws_size,
                              hipStream_t stream) {
    const float* x       = (const float*)d_in[0];
    const float* w_norm  = (const float*)d_in[1];
    const float* b_norm  = (const float*)d_in[2];
    const float* w_in    = (const float*)d_in[3];
    const float* w_conv  = (const float*)d_in[4];
    const float* b_conv  = (const float*)d_in[5];
    const float* A_log   = (const float*)d_in[6];
    const float* w_b     = (const float*)d_in[7];
    const float* w_c     = (const float*)d_in[8];
    const float* w_delta = (const float*)d_in[9];
    const float* b_delta = (const float*)d_in[10];
    const float* D_param = (const float*)d_in[11];
    const float* w_out   = (const float*)d_in[12];
    float* out = (float*)d_out;

    // scratch: use harness ws if big enough, else static device buffer
    char* p = (char*)d_ws;
    if (ws_size < WS_NEEDED) {
        void* sp = nullptr;
        hipGetSymbolAddress(&sp, HIP_SYMBOL(g_scratch));
        p = (char*)sp;
    }
    auto alloc = [&](size_t bytes) { char* q = p; p += (bytes + 255) & ~255ull; return q; };

    bf16* wT_in    = (bf16*)alloc((size_t)4096 * 1024 * 2);   // (2*DIN, D) bf16
    bf16* wT_delta = (bf16*)alloc((size_t)2048 * 2048 * 2);   // (DIN, DIN) bf16
    bf16* wT_out   = (bf16*)alloc((size_t)1024 * 2048 * 2);   // (D, DIN) bf16
    bf16* xn       = (bf16*)alloc((size_t)T_ * D_ * 2);
    bf16* xz       = (bf16*)alloc((size_t)T_ * 2 * DIN * 2);
    bf16* xs       = (bf16*)alloc((size_t)T_ * DIN * 2);
    float* delta   = (float*)alloc((size_t)T_ * DIN * 4);
    float* Bq      = (float*)alloc((size_t)T_ * NST * 4);
    float* Cq      = (float*)alloc((size_t)T_ * NST * 4);
    bf16* gbuf     = (bf16*)alloc((size_t)T_ * DIN * 2);

    // weight transposes + bf16 convert (K-major for GEMM B-operand)
    transpose_f2b<<<dim3(4096 / 32, 1024 / 32), 256, 0, stream>>>(w_in, wT_in, 1024, 4096);
    transpose_f2b<<<dim3(2048 / 32, 2048 / 32), 256, 0, stream>>>(w_delta, wT_delta, 2048, 2048);
    transpose_f2b<<<dim3(1024 / 32, 2048 / 32), 256, 0, stream>>>(w_out, wT_out, 2048, 1024);

    // layernorm (fp32 -> bf16)
    ln_kernel<<<T_, 256, 0, stream>>>(x, w_norm, b_norm, xn);

    // xz = xn @ w_in  (M=4096, N=4096, K=1024) -> bf16
    gemm128<0><<<dim3(4096 / 128, T_ / 128), 256, 0, stream>>>(xn, wT_in, 1024, xz, nullptr, 4096);

    // depthwise causal conv + silu -> xs (bf16)
    conv_kernel<<<dim3(DIN / 256, L_ / 128, B_), 256, 0, stream>>>(xz, w_conv, b_conv, xs);

    // B,C projections (fp32 weights)
    bc_kernel<<<T_, 256, 0, stream>>>(xs, w_b, w_c, Bq, Cq);

    // delta = softplus(xs @ w_delta + b_delta)  (M=4096, N=2048, K=2048) -> fp32
    gemm128<1><<<dim3(2048 / 128, T_ / 128), 256, 0, stream>>>(xs, wT_delta, 2048, delta, b_delta, 2048);

    // selective scan + gating -> gbuf (bf16)
    scan_kernel<<<dim3(256), 256, 0, stream>>>(delta, xs, Bq, Cq, A_log, D_param, xz, gbuf);

    // out = gbuf @ w_out + residual  (M=4096, N=1024, K=2048) -> fp32
    gemm128<2><<<dim3(1024 / 128, T_ / 128), 256, 0, stream>>>(gbuf, wT_out, 2048, out, x, 1024);
}

// Round 5
// 689.175 us; speedup vs baseline: 2.8000x; 2.8000x over previous
//
#include <hip/hip_runtime.h>
#include <hip/hip_bf16.h>

typedef __hip_bfloat16 bf16;
typedef __bf16 bf16x8 __attribute__((ext_vector_type(8)));
typedef float f32x4 __attribute__((ext_vector_type(4)));

#define B_  2
#define L_  2048
#define D_  1024
#define DIN 2048
#define NST 16
#define T_  (B_ * L_)   // 4096 tokens
#define NCH 32          // scan chunks per sequence
#define CH  64          // tokens per chunk

// Static fallback scratch if harness d_ws is too small (~149 MiB needed).
#define WS_NEEDED 155716000ull
__device__ __align__(256) char g_scratch[167772160];   // 160 MiB

__device__ __forceinline__ float b2f(bf16 v) { return __bfloat162float(v); }
__device__ __forceinline__ bf16 f2b(float v) { return __float2bfloat16(v); }

// ---------------------------------------------------------------- transpose + fp32->bf16
// in: R x C (row-major fp32) -> out: C x R (row-major bf16)
__global__ __launch_bounds__(256) void transpose_f2b(const float* __restrict__ in,
                                                     bf16* __restrict__ out, int R, int C) {
    __shared__ float t[32][33];
    int c0 = blockIdx.x * 32, r0 = blockIdx.y * 32;
    int tx = threadIdx.x & 31, ty = threadIdx.x >> 5;   // 32 x 8
    #pragma unroll
    for (int i = 0; i < 32; i += 8)
        t[ty + i][tx] = in[(size_t)(r0 + ty + i) * C + c0 + tx];
    __syncthreads();
    #pragma unroll
    for (int i = 0; i < 32; i += 8)
        out[(size_t)(c0 + ty + i) * R + r0 + tx] = f2b(t[tx][ty + i]);
}

// ---------------------------------------------------------------- layernorm (fp32 in, bf16 out)
__global__ __launch_bounds__(256) void ln_kernel(const float* __restrict__ x,
                                                 const float* __restrict__ w,
                                                 const float* __restrict__ bb,
                                                 bf16* __restrict__ xn) {
    int tok = blockIdx.x, tid = threadIdx.x;
    const float* xr = x + (size_t)tok * D_;
    float4 v4 = ((const float4*)xr)[tid];
    float v[4] = {v4.x, v4.y, v4.z, v4.w};
    float s = 0.f, ss = 0.f;
    #pragma unroll
    for (int i = 0; i < 4; i++) { s += v[i]; ss += v[i] * v[i]; }
    #pragma unroll
    for (int o = 32; o > 0; o >>= 1) { s += __shfl_down(s, o); ss += __shfl_down(ss, o); }
    __shared__ float rs[4], rss[4], mv[2];
    if ((tid & 63) == 0) { rs[tid >> 6] = s; rss[tid >> 6] = ss; }
    __syncthreads();
    if (tid == 0) {
        float S = rs[0] + rs[1] + rs[2] + rs[3];
        float SS = rss[0] + rss[1] + rss[2] + rss[3];
        float mu = S * (1.f / D_);
        float var = SS * (1.f / D_) - mu * mu;
        mv[0] = mu; mv[1] = rsqrtf(fmaxf(var, 0.f) + 1e-5f);
    }
    __syncthreads();
    float mu = mv[0], rstd = mv[1];
    float4 wv = ((const float4*)w)[tid];
    float4 bv = ((const float4*)bb)[tid];
    float wa[4] = {wv.x, wv.y, wv.z, wv.w};
    float ba[4] = {bv.x, bv.y, bv.z, bv.w};
    union { uint2 u; bf16 h[4]; } q;
    #pragma unroll
    for (int i = 0; i < 4; i++)
        q.h[i] = f2b((v[i] - mu) * rstd * wa[i] + ba[i]);
    ((uint2*)(xn + (size_t)tok * D_))[tid] = q.u;
}

// ---------------------------------------------------------------- GEMM 128x128, register-staged LDS
// C[M,N] = A[M,K] @ Bt[N,K]^T
// EPI 0: store bf16 | 1: +bias(fp32), softplus, store fp32 | 2: +resid(fp32), store fp32
template <int EPI>
__global__ __launch_bounds__(256) void gemm128(const bf16* __restrict__ A,
                                               const bf16* __restrict__ Bt,
                                               int K, void* __restrict__ Cout,
                                               const float* __restrict__ extra, int ldc) {
    __shared__ __align__(16) bf16 As[128 * 32];
    __shared__ __align__(16) bf16 Bs[128 * 32];
    const int tid = threadIdx.x;
    const int lane = tid & 63;
    const int wave = tid >> 6;
    const int bm = blockIdx.y * 128, bn = blockIdx.x * 128;
    const int wm = (wave & 1) * 64, wn = (wave >> 1) * 64;
    f32x4 acc[4][4];
    #pragma unroll
    for (int i = 0; i < 4; i++)
        #pragma unroll
        for (int j = 0; j < 4; j++) acc[i][j] = (f32x4){0.f, 0.f, 0.f, 0.f};

    const int r = tid >> 2;   // 0..63: row within 64-row half
    const int c = tid & 3;    // 16B chunk within 64B (32-element) k-slab
    const bf16* ga  = A  + (size_t)(bm + r) * K + c * 8;
    const bf16* gb  = Bt + (size_t)(bn + r) * K + c * 8;
    const bf16* ga2 = ga + (size_t)64 * K;
    const bf16* gb2 = gb + (size_t)64 * K;
    bf16* la  = As + tid * 8;           // element (r*32 + c*8) = row-major [64][32]
    bf16* lb  = Bs + tid * 8;
    bf16* la2 = la + 64 * 32;
    bf16* lb2 = lb + 64 * 32;

    const int fm = lane & 15;
    const int fk = (lane >> 4) * 8;

    for (int k0 = 0; k0 < K; k0 += 32) {
        uint4 va  = *(const uint4*)(ga  + k0);
        uint4 va2 = *(const uint4*)(ga2 + k0);
        uint4 vb  = *(const uint4*)(gb  + k0);
        uint4 vb2 = *(const uint4*)(gb2 + k0);
        __syncthreads();                 // prior iteration's LDS reads complete
        *(uint4*)la  = va;
        *(uint4*)la2 = va2;
        *(uint4*)lb  = vb;
        *(uint4*)lb2 = vb2;
        __syncthreads();                 // stores visible to all waves
        bf16x8 af[4], bfr[4];
        #pragma unroll
        for (int i = 0; i < 4; i++)
            af[i] = *(const bf16x8*)(As + (wm + i * 16 + fm) * 32 + fk);
        #pragma unroll
        for (int j = 0; j < 4; j++)
            bfr[j] = *(const bf16x8*)(Bs + (wn + j * 16 + fm) * 32 + fk);
        #pragma unroll
        for (int i = 0; i < 4; i++)
            #pragma unroll
            for (int j = 0; j < 4; j++)
                acc[i][j] = __builtin_amdgcn_mfma_f32_16x16x32_bf16(af[i], bfr[j], acc[i][j], 0, 0, 0);
    }

    const int cn = lane & 15;
    const int r4 = (lane >> 4) * 4;
    #pragma unroll
    for (int i = 0; i < 4; i++) {
        #pragma unroll
        for (int j = 0; j < 4; j++) {
            int row = bm + wm + i * 16 + r4;
            int col = bn + wn + j * 16 + cn;
            #pragma unroll
            for (int rr = 0; rr < 4; rr++) {
                float v = acc[i][j][rr];
                size_t idx = (size_t)(row + rr) * ldc + col;
                if (EPI == 0) {
                    ((bf16*)Cout)[idx] = f2b(v);
                } else if (EPI == 1) {
                    v += extra[col];
                    float sp = (v > 15.f) ? v : log1pf(__expf(v));
                    sp = fminf(fmaxf(sp, 0.f), 60.f);      // inert clamp
                    ((float*)Cout)[idx] = sp;
                } else {
                    v += extra[idx];
                    ((float*)Cout)[idx] = v;
                }
            }
        }
    }
}

// ---------------------------------------------------------------- depthwise causal conv + SiLU
// xz: (T, 2*DIN) bf16, x_path = cols [0,DIN). out xs: (T, DIN) bf16
__global__ __launch_bounds__(256) void conv_kernel(const bf16* __restrict__ xz,
                                                   const float* __restrict__ wconv,
                                                   const float* __restrict__ bconv,
                                                   bf16* __restrict__ xs) {
    int d = blockIdx.x * 256 + threadIdx.x;   // 0..DIN-1
    int b = blockIdx.z;
    int l0 = blockIdx.y * 128;
    float w0 = wconv[d * 4 + 0];
    float w1 = wconv[d * 4 + 1];
    float w2 = wconv[d * 4 + 2];
    float w3 = wconv[d * 4 + 3];
    float bc = bconv[d];
    const bf16* base = xz + (size_t)(b * L_) * (2 * DIN) + d;
    float xm3 = (l0 >= 3) ? b2f(base[(size_t)(l0 - 3) * (2 * DIN)]) : 0.f;
    float xm2 = (l0 >= 2) ? b2f(base[(size_t)(l0 - 2) * (2 * DIN)]) : 0.f;
    float xm1 = (l0 >= 1) ? b2f(base[(size_t)(l0 - 1) * (2 * DIN)]) : 0.f;
    for (int l = l0; l < l0 + 128; ++l) {
        float cur = b2f(base[(size_t)l * (2 * DIN)]);
        float v = fmaf(w0, xm3, fmaf(w1, xm2, fmaf(w2, xm1, fmaf(w3, cur, bc))));
        float s = v / (1.f + __expf(-v));
        s = fminf(fmaxf(s, -1e4f), 1e4f);                  // inert clamp
        xs[(size_t)(b * L_ + l) * DIN + d] = f2b(s);
        xm3 = xm2; xm2 = xm1; xm1 = cur;
    }
}

// ---------------------------------------------------------------- B/C projections (N=16 each)
__global__ __launch_bounds__(256) void bc_kernel(const bf16* __restrict__ xs,
                                                 const float* __restrict__ wb,
                                                 const float* __restrict__ wc,
                                                 float* __restrict__ Bq, float* __restrict__ Cq) {
    int tok = blockIdx.x;
    __shared__ float xr[DIN];
    __shared__ float red[8][32];
    const bf16* row = xs + (size_t)tok * DIN;
    {
        union { uint4 u; bf16 h[8]; } p;
        p.u = ((const uint4*)row)[threadIdx.x];
        #pragma unroll
        for (int i = 0; i < 8; i++) xr[threadIdx.x * 8 + i] = b2f(p.h[i]);
    }
    __syncthreads();
    int n = threadIdx.x & 31, g = threadIdx.x >> 5;
    const float* w = (n < 16) ? (wb + n) : (wc + (n - 16));
    float p = 0.f;
    int k0 = g * 256;
    for (int k = k0; k < k0 + 256; ++k) p += xr[k] * w[(size_t)k * 16];
    red[g][n] = p;
    __syncthreads();
    if (g == 0) {
        float s = 0.f;
        #pragma unroll
        for (int i = 0; i < 8; i++) s += red[i][n];
        if (n < 16) Bq[(size_t)tok * 16 + n] = s;
        else        Cq[(size_t)tok * 16 + (n - 16)] = s;
    }
}

// ---------------------------------------------------------------- chunked selective scan
// groups of 16 lanes, one per (b, chunk, d); lane = state n.
// ws layout for hend/aprod/hinit: [b][c][d][n]
__global__ __launch_bounds__(256) void scan_passA(const float* __restrict__ delta,
                                                  const bf16* __restrict__ xs,
                                                  const float* __restrict__ Bq,
                                                  const float* __restrict__ A_log,
                                                  float* __restrict__ hend,
                                                  float* __restrict__ aprod) {
    int gid = blockIdx.x * 16 + (threadIdx.x >> 4);
    int n = threadIdx.x & 15;
    int b = gid >> 16;
    int rem = gid & 65535;
    int c = rem >> 11;
    int d = rem & (DIN - 1);
    float A = -__expf(A_log[d * 16 + n]);
    float h = 0.f, ap = 1.f;
    int t0 = b * L_ + c * CH;
    for (int t = t0; t < t0 + CH; ++t) {
        float dlt = delta[(size_t)t * DIN + d];
        float xv = b2f(xs[(size_t)t * DIN + d]);
        float Bv = Bq[(size_t)t * 16 + n];
        float a = __expf(dlt * A);
        h = fmaf(a, h, dlt * xv * Bv);
        ap *= a;
    }
    size_t idx = ((size_t)(b * NCH + c) * DIN + d) * 16 + n;
    hend[idx] = h;
    aprod[idx] = ap;
}

__global__ __launch_bounds__(256) void scan_passB(const float* __restrict__ hend,
                                                  const float* __restrict__ aprod,
                                                  float* __restrict__ hinit) {
    int tid = blockIdx.x * 256 + threadIdx.x;   // (b*DIN+d)*16+n
    int b = tid >> 15;
    int dn = tid & 32767;
    float h = 0.f;
    size_t base = (size_t)b * NCH * DIN * 16 + dn;
    for (int c = 0; c < NCH; ++c) {
        size_t idx = base + (size_t)c * DIN * 16;
        hinit[idx] = h;
        h = fmaf(aprod[idx], h, hend[idx]);
    }
}

__global__ __launch_bounds__(256) void scan_passC(const float* __restrict__ delta,
                                                  const bf16* __restrict__ xs,
                                                  const float* __restrict__ Bq,
                                                  const float* __restrict__ Cq,
                                                  const float* __restrict__ A_log,
                                                  const float* __restrict__ Dp,
                                                  const bf16* __restrict__ xz,
                                                  const float* __restrict__ hinit,
                                                  bf16* __restrict__ gbuf) {
    int gid = blockIdx.x * 16 + (threadIdx.x >> 4);
    int n = threadIdx.x & 15;
    int b = gid >> 16;
    int rem = gid & 65535;
    int c = rem >> 11;
    int d = rem & (DIN - 1);
    float A = -__expf(A_log[d * 16 + n]);
    float Dd = Dp[d];
    float h = hinit[((size_t)(b * NCH + c) * DIN + d) * 16 + n];
    int t0 = b * L_ + c * CH;
    for (int t = t0; t < t0 + CH; ++t) {
        float dlt = delta[(size_t)t * DIN + d];
        float xv = b2f(xs[(size_t)t * DIN + d]);
        float Bv = Bq[(size_t)t * 16 + n];
        float Cv = Cq[(size_t)t * 16 + n];
        float a = __expf(dlt * A);
        h = fmaf(a, h, dlt * xv * Bv);
        float s = h * Cv;
        s += __shfl_xor(s, 1);
        s += __shfl_xor(s, 2);
        s += __shfl_xor(s, 4);
        s += __shfl_xor(s, 8);
        if (n == 0) {
            float zv = b2f(xz[(size_t)t * (2 * DIN) + DIN + d]);
            float y = s + Dd * xv;
            float gg = y * (zv / (1.f + __expf(-zv)));
            gbuf[(size_t)t * DIN + d] = f2b(gg);
        }
    }
}

// ---------------------------------------------------------------- launch
extern "C" void kernel_launch(void* const* d_in, const int* in_sizes, int n_in,
                              void* d_out, int out_size, void* d_ws, size_t ws_size,
                              hipStream_t stream) {
    const float* x       = (const float*)d_in[0];
    const float* w_norm  = (const float*)d_in[1];
    const float* b_norm  = (const float*)d_in[2];
    const float* w_in    = (const float*)d_in[3];
    const float* w_conv  = (const float*)d_in[4];
    const float* b_conv  = (const float*)d_in[5];
    const float* A_log   = (const float*)d_in[6];
    const float* w_b     = (const float*)d_in[7];
    const float* w_c     = (const float*)d_in[8];
    const float* w_delta = (const float*)d_in[9];
    const float* b_delta = (const float*)d_in[10];
    const float* D_param = (const float*)d_in[11];
    const float* w_out   = (const float*)d_in[12];
    float* out = (float*)d_out;

    // scratch: use harness ws if big enough, else static device buffer
    char* p = (char*)d_ws;
    if (ws_size < WS_NEEDED) {
        void* sp = nullptr;
        hipGetSymbolAddress(&sp, HIP_SYMBOL(g_scratch));
        p = (char*)sp;
    }
    auto alloc = [&](size_t bytes) { char* q = p; p += (bytes + 255) & ~255ull; return q; };

    bf16* wT_in    = (bf16*)alloc((size_t)4096 * 1024 * 2);   // (2*DIN, D) bf16
    bf16* wT_delta = (bf16*)alloc((size_t)2048 * 2048 * 2);   // (DIN, DIN) bf16
    bf16* wT_out   = (bf16*)alloc((size_t)1024 * 2048 * 2);   // (D, DIN) bf16
    bf16* xn       = (bf16*)alloc((size_t)T_ * D_ * 2);
    bf16* xz       = (bf16*)alloc((size_t)T_ * 2 * DIN * 2);
    bf16* xs       = (bf16*)alloc((size_t)T_ * DIN * 2);
    float* delta   = (float*)alloc((size_t)T_ * DIN * 4);
    float* Bq      = (float*)alloc((size_t)T_ * NST * 4);
    float* Cq      = (float*)alloc((size_t)T_ * NST * 4);
    bf16* gbuf     = (bf16*)alloc((size_t)T_ * DIN * 2);
    float* hend    = (float*)alloc((size_t)B_ * NCH * DIN * NST * 4);
    float* aprod   = (float*)alloc((size_t)B_ * NCH * DIN * NST * 4);
    float* hinit   = (float*)alloc((size_t)B_ * NCH * DIN * NST * 4);

    // weight transposes + bf16 convert (K-major for GEMM B-operand)
    transpose_f2b<<<dim3(4096 / 32, 1024 / 32), 256, 0, stream>>>(w_in, wT_in, 1024, 4096);
    transpose_f2b<<<dim3(2048 / 32, 2048 / 32), 256, 0, stream>>>(w_delta, wT_delta, 2048, 2048);
    transpose_f2b<<<dim3(1024 / 32, 2048 / 32), 256, 0, stream>>>(w_out, wT_out, 2048, 1024);

    // layernorm (fp32 -> bf16)
    ln_kernel<<<T_, 256, 0, stream>>>(x, w_norm, b_norm, xn);

    // xz = xn @ w_in  (M=4096, N=4096, K=1024) -> bf16
    gemm128<0><<<dim3(4096 / 128, T_ / 128), 256, 0, stream>>>(xn, wT_in, 1024, xz, nullptr, 4096);

    // depthwise causal conv + silu -> xs (bf16)
    conv_kernel<<<dim3(DIN / 256, L_ / 128, B_), 256, 0, stream>>>(xz, w_conv, b_conv, xs);

    // B,C projections (fp32 weights)
    bc_kernel<<<T_, 256, 0, stream>>>(xs, w_b, w_c, Bq, Cq);

    // delta = softplus(xs @ w_delta + b_delta)  (M=4096, N=2048, K=2048) -> fp32
    gemm128<1><<<dim3(2048 / 128, T_ / 128), 256, 0, stream>>>(xs, wT_delta, 2048, delta, b_delta, 2048);

    // chunked selective scan + gating -> gbuf (bf16)
    scan_passA<<<(B_ * NCH * DIN) / 16, 256, 0, stream>>>(delta, xs, Bq, A_log, hend, aprod);
    scan_passB<<<(B_ * DIN * NST) / 256, 256, 0, stream>>>(hend, aprod, hinit);
    scan_passC<<<(B_ * NCH * DIN) / 16, 256, 0, stream>>>(delta, xs, Bq, Cq, A_log, D_param,
                                                          xz, hinit, gbuf);

    // out = gbuf @ w_out + residual  (M=4096, N=1024, K=2048) -> fp32
    gemm128<2><<<dim3(1024 / 128, T_ / 128), 256, 0, stream>>>(gbuf, wT_out, 2048, out, x, 1024);
}

// Round 6
// 460.702 us; speedup vs baseline: 4.1887x; 1.4959x over previous
//
#include <hip/hip_runtime.h>
#include <hip/hip_bf16.h>

typedef __hip_bfloat16 bf16;
typedef __bf16 bf16x8 __attribute__((ext_vector_type(8)));
typedef float f32x4 __attribute__((ext_vector_type(4)));

#define B_  2
#define L_  2048
#define D_  1024
#define DIN 2048
#define NST 16
#define T_  (B_ * L_)   // 4096 tokens
#define NCH 32          // scan chunks per sequence
#define CH  64          // tokens per chunk

// Static fallback scratch if harness d_ws is too small (~165 MiB needed).
#define WS_NEEDED 173000000ull
__device__ __align__(256) char g_scratch[184549376];   // 176 MiB

__device__ __forceinline__ float b2f(bf16 v) { return __bfloat162float(v); }
__device__ __forceinline__ bf16 f2b(float v) { return __float2bfloat16(v); }

__device__ __forceinline__ void async16(const bf16* g, bf16* l) {
    __builtin_amdgcn_global_load_lds((const __attribute__((address_space(1))) unsigned int*)g,
                                     (__attribute__((address_space(3))) unsigned int*)l, 16, 0, 0);
}

// ---------------------------------------------------------------- transpose + fp32->bf16
// in: R x C (row-major fp32) -> out: C x R (row-major bf16)
__global__ __launch_bounds__(256) void transpose_f2b(const float* __restrict__ in,
                                                     bf16* __restrict__ out, int R, int C) {
    __shared__ float t[32][33];
    int c0 = blockIdx.x * 32, r0 = blockIdx.y * 32;
    int tx = threadIdx.x & 31, ty = threadIdx.x >> 5;   // 32 x 8
    #pragma unroll
    for (int i = 0; i < 32; i += 8)
        t[ty + i][tx] = in[(size_t)(r0 + ty + i) * C + c0 + tx];
    __syncthreads();
    #pragma unroll
    for (int i = 0; i < 32; i += 8)
        out[(size_t)(c0 + ty + i) * R + r0 + tx] = f2b(t[tx][ty + i]);
}

// ---------------------------------------------------------------- layernorm (fp32 in, bf16 out)
__global__ __launch_bounds__(256) void ln_kernel(const float* __restrict__ x,
                                                 const float* __restrict__ w,
                                                 const float* __restrict__ bb,
                                                 bf16* __restrict__ xn) {
    int tok = blockIdx.x, tid = threadIdx.x;
    const float* xr = x + (size_t)tok * D_;
    float4 v4 = ((const float4*)xr)[tid];
    float v[4] = {v4.x, v4.y, v4.z, v4.w};
    float s = 0.f, ss = 0.f;
    #pragma unroll
    for (int i = 0; i < 4; i++) { s += v[i]; ss += v[i] * v[i]; }
    #pragma unroll
    for (int o = 32; o > 0; o >>= 1) { s += __shfl_down(s, o); ss += __shfl_down(ss, o); }
    __shared__ float rs[4], rss[4], mv[2];
    if ((tid & 63) == 0) { rs[tid >> 6] = s; rss[tid >> 6] = ss; }
    __syncthreads();
    if (tid == 0) {
        float S = rs[0] + rs[1] + rs[2] + rs[3];
        float SS = rss[0] + rss[1] + rss[2] + rss[3];
        float mu = S * (1.f / D_);
        float var = SS * (1.f / D_) - mu * mu;
        mv[0] = mu; mv[1] = rsqrtf(fmaxf(var, 0.f) + 1e-5f);
    }
    __syncthreads();
    float mu = mv[0], rstd = mv[1];
    float4 wv = ((const float4*)w)[tid];
    float4 bv = ((const float4*)bb)[tid];
    float wa[4] = {wv.x, wv.y, wv.z, wv.w};
    float ba[4] = {bv.x, bv.y, bv.z, bv.w};
    union { uint2 u; bf16 h[4]; } q;
    #pragma unroll
    for (int i = 0; i < 4; i++)
        q.h[i] = f2b((v[i] - mu) * rstd * wa[i] + ba[i]);
    ((uint2*)(xn + (size_t)tok * D_))[tid] = q.u;
}

// ---------------------------------------------------------------- GEMM 128x128, async LDS staging
// C[M,N] = A[M,K] @ Bt[N,K]^T
// EPI 0: store bf16 | 1: +bias(fp32), softplus, store fp32 | 2: +resid(fp32), store fp32
template <int EPI>
__global__ __launch_bounds__(256) void gemm128(const bf16* __restrict__ A,
                                               const bf16* __restrict__ Bt,
                                               int K, void* __restrict__ Cout,
                                               const float* __restrict__ extra, int ldc) {
    __shared__ __align__(16) bf16 As[128 * 32];
    __shared__ __align__(16) bf16 Bs[128 * 32];
    const int tid = threadIdx.x;
    const int lane = tid & 63;
    const int wave = tid >> 6;
    const int bm = blockIdx.y * 128, bn = blockIdx.x * 128;
    const int wm = (wave & 1) * 64, wn = (wave >> 1) * 64;
    f32x4 acc[4][4];
    #pragma unroll
    for (int i = 0; i < 4; i++)
        #pragma unroll
        for (int j = 0; j < 4; j++) acc[i][j] = (f32x4){0.f, 0.f, 0.f, 0.f};

    const int r = tid >> 2;   // 0..63: row within 64-row half
    const int c = tid & 3;    // 16B chunk within 64B (32-element) k-slab
    const bf16* ga  = A  + (size_t)(bm + r) * K + c * 8;
    const bf16* gb  = Bt + (size_t)(bn + r) * K + c * 8;
    const bf16* ga2 = ga + (size_t)64 * K;
    const bf16* gb2 = gb + (size_t)64 * K;
    bf16* la  = As + tid * 8;           // lane addr = wave-uniform base + lane*16B
    bf16* lb  = Bs + tid * 8;
    bf16* la2 = la + 64 * 32;
    bf16* lb2 = lb + 64 * 32;

    const int fm = lane & 15;
    const int fk = (lane >> 4) * 8;

    for (int k0 = 0; k0 < K; k0 += 32) {
        async16(ga + k0, la);
        async16(ga2 + k0, la2);
        async16(gb + k0, lb);
        async16(gb2 + k0, lb2);
        __syncthreads();                 // drains vmcnt: staged data visible
        bf16x8 af[4], bfr[4];
        #pragma unroll
        for (int i = 0; i < 4; i++)
            af[i] = *(const bf16x8*)(As + (wm + i * 16 + fm) * 32 + fk);
        #pragma unroll
        for (int j = 0; j < 4; j++)
            bfr[j] = *(const bf16x8*)(Bs + (wn + j * 16 + fm) * 32 + fk);
        #pragma unroll
        for (int i = 0; i < 4; i++)
            #pragma unroll
            for (int j = 0; j < 4; j++)
                acc[i][j] = __builtin_amdgcn_mfma_f32_16x16x32_bf16(af[i], bfr[j], acc[i][j], 0, 0, 0);
        __syncthreads();                 // LDS reads done before next stage
    }

    const int cn = lane & 15;
    const int r4 = (lane >> 4) * 4;
    #pragma unroll
    for (int i = 0; i < 4; i++) {
        #pragma unroll
        for (int j = 0; j < 4; j++) {
            int row = bm + wm + i * 16 + r4;
            int col = bn + wn + j * 16 + cn;
            #pragma unroll
            for (int rr = 0; rr < 4; rr++) {
                float v = acc[i][j][rr];
                size_t idx = (size_t)(row + rr) * ldc + col;
                if (EPI == 0) {
                    ((bf16*)Cout)[idx] = f2b(v);
                } else if (EPI == 1) {
                    v += extra[col];
                    float sp = (v > 15.f) ? v : log1pf(__expf(v));
                    sp = fminf(fmaxf(sp, 0.f), 60.f);
                    ((float*)Cout)[idx] = sp;
                } else {
                    v += extra[idx];
                    ((float*)Cout)[idx] = v;
                }
            }
        }
    }
}

// ---------------------------------------------------------------- depthwise causal conv + SiLU
__global__ __launch_bounds__(256) void conv_kernel(const bf16* __restrict__ xz,
                                                   const float* __restrict__ wconv,
                                                   const float* __restrict__ bconv,
                                                   bf16* __restrict__ xs) {
    int d = blockIdx.x * 256 + threadIdx.x;
    int b = blockIdx.z;
    int l0 = blockIdx.y * 128;
    float w0 = wconv[d * 4 + 0];
    float w1 = wconv[d * 4 + 1];
    float w2 = wconv[d * 4 + 2];
    float w3 = wconv[d * 4 + 3];
    float bc = bconv[d];
    const bf16* base = xz + (size_t)(b * L_) * (2 * DIN) + d;
    float xm3 = (l0 >= 3) ? b2f(base[(size_t)(l0 - 3) * (2 * DIN)]) : 0.f;
    float xm2 = (l0 >= 2) ? b2f(base[(size_t)(l0 - 2) * (2 * DIN)]) : 0.f;
    float xm1 = (l0 >= 1) ? b2f(base[(size_t)(l0 - 1) * (2 * DIN)]) : 0.f;
    for (int l = l0; l < l0 + 128; ++l) {
        float cur = b2f(base[(size_t)l * (2 * DIN)]);
        float v = fmaf(w0, xm3, fmaf(w1, xm2, fmaf(w2, xm1, fmaf(w3, cur, bc))));
        float s = v / (1.f + __expf(-v));
        xs[(size_t)(b * L_ + l) * DIN + d] = f2b(s);
        xm3 = xm2; xm2 = xm1; xm1 = cur;
    }
}

// ---------------------------------------------------------------- B/C projections (N=16 each)
__global__ __launch_bounds__(256) void bc_kernel(const bf16* __restrict__ xs,
                                                 const float* __restrict__ wb,
                                                 const float* __restrict__ wc,
                                                 float* __restrict__ Bq, float* __restrict__ Cq) {
    int tok = blockIdx.x;
    __shared__ float xr[DIN];
    __shared__ float red[8][32];
    const bf16* row = xs + (size_t)tok * DIN;
    {
        union { uint4 u; bf16 h[8]; } p;
        p.u = ((const uint4*)row)[threadIdx.x];
        #pragma unroll
        for (int i = 0; i < 8; i++) xr[threadIdx.x * 8 + i] = b2f(p.h[i]);
    }
    __syncthreads();
    int n = threadIdx.x & 31, g = threadIdx.x >> 5;
    const float* w = (n < 16) ? (wb + n) : (wc + (n - 16));
    float p = 0.f;
    int k0 = g * 256;
    for (int k = k0; k < k0 + 256; ++k) p += xr[k] * w[(size_t)k * 16];
    red[g][n] = p;
    __syncthreads();
    if (g == 0) {
        float s = 0.f;
        #pragma unroll
        for (int i = 0; i < 8; i++) s += red[i][n];
        if (n < 16) Bq[(size_t)tok * 16 + n] = s;
        else        Cq[(size_t)tok * 16 + (n - 16)] = s;
    }
}

// ---------------------------------------------------------------- chunked selective scan
// thread per (b, chunk, d); 16 states in registers. hend/aprod/hinit: [b][c][d][n]
__global__ __launch_bounds__(256) void scan_passA(const float* __restrict__ delta,
                                                  const bf16* __restrict__ xs,
                                                  const float* __restrict__ Bq,
                                                  const float* __restrict__ A_log,
                                                  float* __restrict__ hend,
                                                  float* __restrict__ aprod) {
    __shared__ float Bsh[CH * 16];
    const int d = blockIdx.x * 256 + threadIdx.x;
    const int c = blockIdx.y, b = blockIdx.z;
    const int t0 = b * L_ + c * CH;
    for (int i = threadIdx.x; i < CH * 16; i += 256)
        Bsh[i] = Bq[(size_t)t0 * 16 + i];
    float A[NST], h[NST], ap[NST];
    {
        const float4* al = (const float4*)(A_log + d * 16);
        #pragma unroll
        for (int q = 0; q < 4; q++) {
            float4 v = al[q];
            A[q * 4 + 0] = -__expf(v.x); A[q * 4 + 1] = -__expf(v.y);
            A[q * 4 + 2] = -__expf(v.z); A[q * 4 + 3] = -__expf(v.w);
        }
    }
    #pragma unroll
    for (int n = 0; n < NST; n++) { h[n] = 0.f; ap[n] = 1.f; }
    __syncthreads();
    for (int tt = 0; tt < CH; ++tt) {
        int t = t0 + tt;
        float dlt = delta[(size_t)t * DIN + d];
        float dx = dlt * b2f(xs[(size_t)t * DIN + d]);
        #pragma unroll
        for (int n = 0; n < NST; n++) {
            float a = __expf(dlt * A[n]);
            h[n] = fmaf(a, h[n], dx * Bsh[tt * 16 + n]);
            ap[n] *= a;
        }
    }
    size_t base = ((size_t)(b * NCH + c) * DIN + d) * 16;
    #pragma unroll
    for (int q = 0; q < 4; q++) {
        ((float4*)(hend + base))[q]  = (float4){h[q*4], h[q*4+1], h[q*4+2], h[q*4+3]};
        ((float4*)(aprod + base))[q] = (float4){ap[q*4], ap[q*4+1], ap[q*4+2], ap[q*4+3]};
    }
}

__global__ __launch_bounds__(256) void scan_passB(const float* __restrict__ hend,
                                                  const float* __restrict__ aprod,
                                                  float* __restrict__ hinit) {
    int tid = blockIdx.x * 256 + threadIdx.x;   // (b*DIN+d)*16+n
    int b = tid >> 15;
    int dn = tid & 32767;
    float h = 0.f;
    size_t base = (size_t)b * NCH * DIN * 16 + dn;
    for (int c = 0; c < NCH; ++c) {
        size_t idx = base + (size_t)c * DIN * 16;
        hinit[idx] = h;
        h = fmaf(aprod[idx], h, hend[idx]);
    }
}

__global__ __launch_bounds__(256) void scan_passC(const float* __restrict__ delta,
                                                  const bf16* __restrict__ xs,
                                                  const float* __restrict__ Bq,
                                                  const float* __restrict__ Cq,
                                                  const float* __restrict__ A_log,
                                                  const float* __restrict__ Dp,
                                                  const bf16* __restrict__ xz,
                                                  const float* __restrict__ hinit,
                                                  bf16* __restrict__ gbuf) {
    __shared__ float Bsh[CH * 16];
    __shared__ float Csh[CH * 16];
    const int d = blockIdx.x * 256 + threadIdx.x;
    const int c = blockIdx.y, b = blockIdx.z;
    const int t0 = b * L_ + c * CH;
    for (int i = threadIdx.x; i < CH * 16; i += 256) {
        Bsh[i] = Bq[(size_t)t0 * 16 + i];
        Csh[i] = Cq[(size_t)t0 * 16 + i];
    }
    float A[NST], h[NST];
    {
        const float4* al = (const float4*)(A_log + d * 16);
        #pragma unroll
        for (int q = 0; q < 4; q++) {
            float4 v = al[q];
            A[q * 4 + 0] = -__expf(v.x); A[q * 4 + 1] = -__expf(v.y);
            A[q * 4 + 2] = -__expf(v.z); A[q * 4 + 3] = -__expf(v.w);
        }
    }
    {
        size_t base = ((size_t)(b * NCH + c) * DIN + d) * 16;
        #pragma unroll
        for (int q = 0; q < 4; q++) {
            float4 v = ((const float4*)(hinit + base))[q];
            h[q * 4 + 0] = v.x; h[q * 4 + 1] = v.y; h[q * 4 + 2] = v.z; h[q * 4 + 3] = v.w;
        }
    }
    float Dd = Dp[d];
    __syncthreads();
    for (int tt = 0; tt < CH; ++tt) {
        int t = t0 + tt;
        float dlt = delta[(size_t)t * DIN + d];
        float xv = b2f(xs[(size_t)t * DIN + d]);
        float dx = dlt * xv;
        float y = Dd * xv;
        #pragma unroll
        for (int n = 0; n < NST; n++) {
            float a = __expf(dlt * A[n]);
            h[n] = fmaf(a, h[n], dx * Bsh[tt * 16 + n]);
            y = fmaf(h[n], Csh[tt * 16 + n], y);
        }
        float zv = b2f(xz[(size_t)t * (2 * DIN) + DIN + d]);
        float gg = y * (zv / (1.f + __expf(-zv)));
        gbuf[(size_t)t * DIN + d] = f2b(gg);
    }
}

// ---------------------------------------------------------------- launch
extern "C" void kernel_launch(void* const* d_in, const int* in_sizes, int n_in,
                              void* d_out, int out_size, void* d_ws, size_t ws_size,
                              hipStream_t stream) {
    const float* x       = (const float*)d_in[0];
    const float* w_norm  = (const float*)d_in[1];
    const float* b_norm  = (const float*)d_in[2];
    const float* w_in    = (const float*)d_in[3];
    const float* w_conv  = (const float*)d_in[4];
    const float* b_conv  = (const float*)d_in[5];
    const float* A_log   = (const float*)d_in[6];
    const float* w_b     = (const float*)d_in[7];
    const float* w_c     = (const float*)d_in[8];
    const float* w_delta = (const float*)d_in[9];
    const float* b_delta = (const float*)d_in[10];
    const float* D_param = (const float*)d_in[11];
    const float* w_out   = (const float*)d_in[12];
    float* out = (float*)d_out;

    char* p = (char*)d_ws;
    if (ws_size < WS_NEEDED) {
        void* sp = nullptr;
        hipGetSymbolAddress(&sp, HIP_SYMBOL(g_scratch));
        p = (char*)sp;
    }
    auto alloc = [&](size_t bytes) { char* q = p; p += (bytes + 255) & ~255ull; return q; };

    bf16* wT_in    = (bf16*)alloc((size_t)4096 * 1024 * 2);
    bf16* wT_delta = (bf16*)alloc((size_t)2048 * 2048 * 2);
    bf16* wT_out   = (bf16*)alloc((size_t)1024 * 2048 * 2);
    bf16* xn       = (bf16*)alloc((size_t)T_ * D_ * 2);
    bf16* xz       = (bf16*)alloc((size_t)T_ * 2 * DIN * 2);
    bf16* xs       = (bf16*)alloc((size_t)T_ * DIN * 2);
    float* delta   = (float*)alloc((size_t)T_ * DIN * 4);
    float* Bq      = (float*)alloc((size_t)T_ * NST * 4);
    float* Cq      = (float*)alloc((size_t)T_ * NST * 4);
    bf16* gbuf     = (bf16*)alloc((size_t)T_ * DIN * 2);
    float* hend    = (float*)alloc((size_t)B_ * NCH * DIN * NST * 4);
    float* aprod   = (float*)alloc((size_t)B_ * NCH * DIN * NST * 4);
    float* hinit   = (float*)alloc((size_t)B_ * NCH * DIN * NST * 4);

    transpose_f2b<<<dim3(4096 / 32, 1024 / 32), 256, 0, stream>>>(w_in, wT_in, 1024, 4096);
    transpose_f2b<<<dim3(2048 / 32, 2048 / 32), 256, 0, stream>>>(w_delta, wT_delta, 2048, 2048);
    transpose_f2b<<<dim3(1024 / 32, 2048 / 32), 256, 0, stream>>>(w_out, wT_out, 2048, 1024);

    ln_kernel<<<T_, 256, 0, stream>>>(x, w_norm, b_norm, xn);

    gemm128<0><<<dim3(4096 / 128, T_ / 128), 256, 0, stream>>>(xn, wT_in, 1024, xz, nullptr, 4096);

    conv_kernel<<<dim3(DIN / 256, L_ / 128, B_), 256, 0, stream>>>(xz, w_conv, b_conv, xs);

    bc_kernel<<<T_, 256, 0, stream>>>(xs, w_b, w_c, Bq, Cq);

    gemm128<1><<<dim3(2048 / 128, T_ / 128), 256, 0, stream>>>(xs, wT_delta, 2048, delta, b_delta, 2048);

    scan_passA<<<dim3(DIN / 256, NCH, B_), 256, 0, stream>>>(delta, xs, Bq, A_log, hend, aprod);
    scan_passB<<<(B_ * DIN * NST) / 256, 256, 0, stream>>>(hend, aprod, hinit);
    scan_passC<<<dim3(DIN / 256, NCH, B_), 256, 0, stream>>>(delta, xs, Bq, Cq, A_log, D_param,
                                                             xz, hinit, gbuf);

    gemm128<2><<<dim3(1024 / 128, T_ / 128), 256, 0, stream>>>(gbuf, wT_out, 2048, out, x, 1024);
}